// Round 3
// baseline (206.017 us; speedup 1.0000x reference)
//
#include <hip/hip_runtime.h>
#include <math.h>

#define N_ROWS 8192
#define D_DIM  512
#define C_CLS  100

typedef unsigned short u16;
typedef unsigned int u32;
typedef __attribute__((ext_vector_type(8))) short short8;
typedef __attribute__((ext_vector_type(4))) float floatx4;

// ---------------- ws layout (float offsets), ~68.3 MB ----------------
#define WS_G      0                    // 512*512 fp32
#define WS_GP     262144               // 32 * 512*512 fp32 partials
#define WS_INV    8650752              // 8192
#define WS_WV     8658944              // 8192
#define WS_CLS    8667136              // 8192 (int)
#define WS_CNT    8675328              // 128 (int)
#define WS_OFFS   8675456              // 128 (int)
#define WS_CUR    8675584              // 128 (int)
#define WS_ORDER  8675712              // 8192 (int)
#define WS_NTH    8683904              // 512*8192 u16 = 2097152 floats
#define WS_NTL    10781056
#define WS_XTH    12878208
#define WS_XTL    14975360

// split fp32 -> bf16 hi (chop) + bf16 lo (chop of remainder); rel err ~2^-16
__device__ __forceinline__ void split2(float v, u16& h, u16& l) {
    unsigned u = __float_as_uint(v);
    h = (u16)(u >> 16);
    float r = v - __uint_as_float(u & 0xFFFF0000u);
    l = (u16)(__float_as_uint(r) >> 16);
}

// async global -> LDS, 16 B per lane (global_load_lds_dwordx4)
typedef const __attribute__((address_space(1))) u32* gp32;
typedef __attribute__((address_space(3))) u32* lp32;
__device__ __forceinline__ void cp16(const u16* g, u16* l) {
    __builtin_amdgcn_global_load_lds((gp32)g, (lp32)l, 16, 0, 0);
}

// -------- K1: per-row softmax max + argmax + int class counts --------
__global__ void k_softmax(const float* __restrict__ logits,
                          float* __restrict__ wv, int* __restrict__ cls,
                          int* __restrict__ cnt) {
    int wave = (blockIdx.x * blockDim.x + threadIdx.x) >> 6;
    int lane = threadIdx.x & 63;
    if (wave >= N_ROWS) return;
    const float* row = logits + (size_t)wave * C_CLS;
    float v1 = row[lane];
    bool has2 = (lane + 64) < C_CLS;
    float v2 = has2 ? row[lane + 64] : -INFINITY;
    float m; int idx;
    if (v2 > v1) { m = v2; idx = lane + 64; } else { m = v1; idx = lane; }
    #pragma unroll
    for (int off = 32; off >= 1; off >>= 1) {
        float om = __shfl_down(m, off);
        int   oi = __shfl_down(idx, off);
        if (om > m || (om == m && oi < idx)) { m = om; idx = oi; }
    }
    m = __shfl(m, 0);
    idx = __shfl(idx, 0);
    float s = expf(v1 - m) + (has2 ? expf(v2 - m) : 0.0f);
    #pragma unroll
    for (int off = 32; off >= 1; off >>= 1) s += __shfl_down(s, off);
    if (lane == 0) {
        wv[wave] = 1.0f / s;          // max of softmax = 1/sum(exp(l-lmax))
        cls[wave] = idx;
        atomicAdd(&cnt[idx], 1);
    }
}

// -------- K2: per-row inverse norm --------
__global__ void k_norm(const float* __restrict__ x, float* __restrict__ inv) {
    int wave = (blockIdx.x * blockDim.x + threadIdx.x) >> 6;
    int lane = threadIdx.x & 63;
    if (wave >= N_ROWS) return;
    const float* row = x + (size_t)wave * D_DIM;
    float ss = 0.f;
    #pragma unroll
    for (int j = 0; j < D_DIM; j += 64) {
        float v = row[j + lane];
        ss += v * v;
    }
    #pragma unroll
    for (int off = 32; off >= 1; off >>= 1) ss += __shfl_down(ss, off);
    if (lane == 0) inv[wave] = 1.0f / fmaxf(sqrtf(ss), 1e-8f);
}

// -------- K3: exclusive prefix over class counts (tiny) --------
__global__ void k_scan(const int* __restrict__ cnt, int* __restrict__ offs) {
    if (threadIdx.x == 0) {
        int acc = 0;
        for (int c = 0; c < C_CLS; ++c) { offs[c] = acc; acc += cnt[c]; }
    }
}

// -------- K4: scatter row indices into class-sorted order --------
__global__ void k_scatter(const int* __restrict__ cls, const int* __restrict__ offs,
                          int* __restrict__ cursor, int* __restrict__ order) {
    int m = blockIdx.x * 256 + threadIdx.x;
    int c = cls[m];
    int pos = atomicAdd(&cursor[c], 1);
    order[offs[c] + pos] = m;
}

// -------- K5: split + transpose: x -> xt hi/lo, (inv*x) -> nt hi/lo --------
#define LDT 65
__global__ __launch_bounds__(256) void k_convert(const float* __restrict__ x,
        const float* __restrict__ inv,
        u16* __restrict__ xth, u16* __restrict__ xtl,
        u16* __restrict__ nth, u16* __restrict__ ntl) {
    __shared__ unsigned xt_p[64 * LDT];
    __shared__ unsigned nt_p[64 * LDT];
    int r0 = blockIdx.x * 64, c0 = blockIdx.y * 64;
    int t = threadIdx.x;
    int r = t >> 2, cq = t & 3;
    const float* src = x + (size_t)(r0 + r) * D_DIM + c0 + cq * 16;
    float vv[16];
    {
        float4 a = *(const float4*)(src + 0);
        float4 b = *(const float4*)(src + 4);
        float4 c = *(const float4*)(src + 8);
        float4 d = *(const float4*)(src + 12);
        vv[0]=a.x; vv[1]=a.y; vv[2]=a.z; vv[3]=a.w;
        vv[4]=b.x; vv[5]=b.y; vv[6]=b.z; vv[7]=b.w;
        vv[8]=c.x; vv[9]=c.y; vv[10]=c.z; vv[11]=c.w;
        vv[12]=d.x; vv[13]=d.y; vv[14]=d.z; vv[15]=d.w;
    }
    float iv = inv[r0 + r];
    #pragma unroll
    for (int j = 0; j < 16; ++j) {
        u16 h, l, nh, nl;
        split2(vv[j], h, l);
        split2(iv * vv[j], nh, nl);
        int cl = cq * 16 + j;
        xt_p[cl * LDT + r] = ((unsigned)h  << 16) | l;
        nt_p[cl * LDT + r] = ((unsigned)nh << 16) | nl;
    }
    __syncthreads();
    int c = t >> 2, rq = (t & 3) * 16;
    size_t tbase = (size_t)(c0 + c) * N_ROWS + r0 + rq;
    {
        uint oh[8], ol[8];
        #pragma unroll
        for (int p = 0; p < 8; ++p) {
            unsigned d0 = xt_p[c * LDT + rq + 2*p];
            unsigned d1 = xt_p[c * LDT + rq + 2*p + 1];
            oh[p] = (d0 >> 16) | (d1 & 0xFFFF0000u);
            ol[p] = (d0 & 0xFFFFu) | (d1 << 16);
        }
        *(uint4*)&xth[tbase]     = make_uint4(oh[0], oh[1], oh[2], oh[3]);
        *(uint4*)&xth[tbase + 8] = make_uint4(oh[4], oh[5], oh[6], oh[7]);
        *(uint4*)&xtl[tbase]     = make_uint4(ol[0], ol[1], ol[2], ol[3]);
        *(uint4*)&xtl[tbase + 8] = make_uint4(ol[4], ol[5], ol[6], ol[7]);
    }
    {
        uint oh[8], ol[8];
        #pragma unroll
        for (int p = 0; p < 8; ++p) {
            unsigned d0 = nt_p[c * LDT + rq + 2*p];
            unsigned d1 = nt_p[c * LDT + rq + 2*p + 1];
            oh[p] = (d0 >> 16) | (d1 & 0xFFFF0000u);
            ol[p] = (d0 & 0xFFFFu) | (d1 << 16);
        }
        *(uint4*)&nth[tbase]     = make_uint4(oh[0], oh[1], oh[2], oh[3]);
        *(uint4*)&nth[tbase + 8] = make_uint4(oh[4], oh[5], oh[6], oh[7]);
        *(uint4*)&ntl[tbase]     = make_uint4(ol[0], ol[1], ol[2], ol[3]);
        *(uint4*)&ntl[tbase + 8] = make_uint4(ol[4], ol[5], ol[6], ol[7]);
    }
}

// -------- K6: G_part = nt^T @ xt, 128x128 tiles, splitK=32, m97-style --------
// 4 waves, each 64x64 (4x4 frags of 16x16x32), 3-pass split-bf16.
__global__ __launch_bounds__(256, 2) void k_gemm1(const u16* __restrict__ nth,
        const u16* __restrict__ ntl, const u16* __restrict__ xth,
        const u16* __restrict__ xtl, float* __restrict__ Gp) {
    __shared__ __attribute__((aligned(16))) u16 Ah[128*32], Al[128*32];
    __shared__ __attribute__((aligned(16))) u16 Bh[128*32], Bl[128*32];
    int i0 = (blockIdx.x & 3) << 7, j0 = (blockIdx.x >> 2) << 7;
    int kb = blockIdx.y << 8;                // K-chunk of 256
    int t = threadIdx.x, w = t >> 6, l = t & 63;
    int srow = t >> 2, scol = (t & 3) << 3;
    int lm = l & 15, lg = l >> 4;
    floatx4 acc[4][4];
    #pragma unroll
    for (int mi = 0; mi < 4; ++mi)
        #pragma unroll
        for (int ni = 0; ni < 4; ++ni) acc[mi][ni] = (floatx4){0.f,0.f,0.f,0.f};
    int d0 = srow * 32 + scol;
    int d1 = (64 + srow) * 32 + scol;
    const size_t ga0 = (size_t)(i0 + srow) * N_ROWS + kb + scol;
    const size_t ga1 = (size_t)(i0 + 64 + srow) * N_ROWS + kb + scol;
    const size_t gb0 = (size_t)(j0 + srow) * N_ROWS + kb + scol;
    const size_t gb1 = (size_t)(j0 + 64 + srow) * N_ROWS + kb + scol;
    for (int s = 0; s < 8; ++s) {
        int ks = s << 5;
        cp16(nth + ga0 + ks, Ah + d0);
        cp16(nth + ga1 + ks, Ah + d1);
        cp16(ntl + ga0 + ks, Al + d0);
        cp16(ntl + ga1 + ks, Al + d1);
        cp16(xth + gb0 + ks, Bh + d0);
        cp16(xth + gb1 + ks, Bh + d1);
        cp16(xtl + gb0 + ks, Bl + d0);
        cp16(xtl + gb1 + ks, Bl + d1);
        __syncthreads();
        short8 ah[4], al[4], bh[4], bl[4];
        #pragma unroll
        for (int mi = 0; mi < 4; ++mi) {
            int off = (((w & 1) << 6) + (mi << 4) + lm) * 32 + (lg << 3);
            ah[mi] = *(const short8*)&Ah[off];
            al[mi] = *(const short8*)&Al[off];
        }
        #pragma unroll
        for (int ni = 0; ni < 4; ++ni) {
            int off = (((w >> 1) << 6) + (ni << 4) + lm) * 32 + (lg << 3);
            bh[ni] = *(const short8*)&Bh[off];
            bl[ni] = *(const short8*)&Bl[off];
        }
        #pragma unroll
        for (int mi = 0; mi < 4; ++mi)
            #pragma unroll
            for (int ni = 0; ni < 4; ++ni) {
                acc[mi][ni] = __builtin_amdgcn_mfma_f32_16x16x32_bf16(ah[mi], bh[ni], acc[mi][ni], 0, 0, 0);
                acc[mi][ni] = __builtin_amdgcn_mfma_f32_16x16x32_bf16(ah[mi], bl[ni], acc[mi][ni], 0, 0, 0);
                acc[mi][ni] = __builtin_amdgcn_mfma_f32_16x16x32_bf16(al[mi], bh[ni], acc[mi][ni], 0, 0, 0);
            }
        __syncthreads();
    }
    float* Gb = Gp + ((size_t)blockIdx.y << 18);
    #pragma unroll
    for (int mi = 0; mi < 4; ++mi) {
        int row0 = i0 + ((w & 1) << 6) + (mi << 4) + (lg << 2);
        #pragma unroll
        for (int ni = 0; ni < 4; ++ni) {
            int col = j0 + ((w >> 1) << 6) + (ni << 4) + lm;
            #pragma unroll
            for (int r = 0; r < 4; ++r)
                Gb[(size_t)(row0 + r) * D_DIM + col] = acc[mi][ni][r];
        }
    }
}

// -------- K7: G = sum of 32 partials --------
__global__ void k_reduceG(const float* __restrict__ Gp, float* __restrict__ G) {
    int i = blockIdx.x * 256 + threadIdx.x;
    float s = 0.f;
    #pragma unroll
    for (int p = 0; p < 32; ++p) s += Gp[(size_t)p * (D_DIM * D_DIM) + i];
    G[i] = s;
}

// -------- K8: per-class u,v then prototypes = (u@G + v)/cnt --------
// block = one class; u_c = sum w*inv*x_m, v_c = sum w*x_m over class rows.
__global__ __launch_bounds__(256) void k_protos(const float* __restrict__ x,
        const float* __restrict__ inv, const float* __restrict__ wv,
        const int* __restrict__ order, const int* __restrict__ offs,
        const int* __restrict__ cnt, const float* __restrict__ G,
        float* __restrict__ out) {
    __shared__ float u_s[D_DIM];
    int c = blockIdx.x;
    int t = threadIdx.x;
    int n = cnt[c], o = offs[c];
    float u0 = 0.f, u1 = 0.f, v0 = 0.f, v1 = 0.f;
    for (int p = 0; p < n; ++p) {
        int m = order[o + p];
        float wm = wv[m];
        float wi = wm * inv[m];
        float xa = x[(size_t)m * D_DIM + t];
        float xb = x[(size_t)m * D_DIM + t + 256];
        u0 += wi * xa; u1 += wi * xb;
        v0 += wm * xa; v1 += wm * xb;
    }
    u_s[t] = u0; u_s[t + 256] = u1;
    __syncthreads();
    float a0 = v0, a1 = v1;
    for (int k = 0; k < D_DIM; ++k) {
        float uk = u_s[k];
        const float* Gr = G + (size_t)k * D_DIM;
        a0 += uk * Gr[t];
        a1 += uk * Gr[t + 256];
    }
    float s = (n > 0) ? 1.0f / (float)n : 0.0f;
    out[(size_t)c * D_DIM + t]       = a0 * s;
    out[(size_t)c * D_DIM + t + 256] = a1 * s;
}

// -------- K9: inter[i,j,d] = proto[j,d] - proto[i,d] --------
__global__ void k_inter(const float* __restrict__ proto, float* __restrict__ out) {
    int pair = blockIdx.x;
    int i = pair / C_CLS;
    int j = pair - i * C_CLS;
    int d = threadIdx.x << 2;
    float4 pj = *(const float4*)&proto[j * D_DIM + d];
    float4 pi = *(const float4*)&proto[i * D_DIM + d];
    float4 r;
    r.x = pj.x - pi.x; r.y = pj.y - pi.y; r.z = pj.z - pi.z; r.w = pj.w - pi.w;
    *(float4*)&out[(size_t)pair * D_DIM + d] = r;
}

extern "C" void kernel_launch(void* const* d_in, const int* in_sizes, int n_in,
                              void* d_out, int out_size, void* d_ws, size_t ws_size,
                              hipStream_t stream) {
    const float* x      = (const float*)d_in[0];   // [8192, 512]
    const float* logits = (const float*)d_in[1];   // [8192, 100]
    float* out = (float*)d_out;
    float* ws  = (float*)d_ws;
    float* G     = ws + WS_G;
    float* Gp    = ws + WS_GP;
    float* inv   = ws + WS_INV;
    float* wv    = ws + WS_WV;
    int*   cls   = (int*)(ws + WS_CLS);
    int*   cnt   = (int*)(ws + WS_CNT);
    int*   offs  = (int*)(ws + WS_OFFS);
    int*   cur   = (int*)(ws + WS_CUR);
    int*   order = (int*)(ws + WS_ORDER);
    u16* nth = (u16*)(ws + WS_NTH);
    u16* ntl = (u16*)(ws + WS_NTL);
    u16* xth = (u16*)(ws + WS_XTH);
    u16* xtl = (u16*)(ws + WS_XTL);

    // zero cnt + offs + cur (384 ints)
    hipMemsetAsync((void*)cnt, 0, 384 * sizeof(int), stream);
    k_softmax<<<N_ROWS / 4, 256, 0, stream>>>(logits, wv, cls, cnt);
    k_norm<<<N_ROWS / 4, 256, 0, stream>>>(x, inv);
    k_scan<<<1, 64, 0, stream>>>(cnt, offs);
    k_scatter<<<N_ROWS / 256, 256, 0, stream>>>(cls, offs, cur, order);
    k_convert<<<dim3(128, 8), 256, 0, stream>>>(x, inv, xth, xtl, nth, ntl);
    k_gemm1<<<dim3(16, 32), 256, 0, stream>>>(nth, ntl, xth, xtl, Gp);
    k_reduceG<<<D_DIM * D_DIM / 256, 256, 0, stream>>>(Gp, G);
    k_protos<<<C_CLS, 256, 0, stream>>>(x, inv, wv, order, offs, cnt, G, out);
    k_inter<<<C_CLS * C_CLS, 128, 0, stream>>>(out, out + C_CLS * D_DIM);
}

// Round 4
// 199.914 us; speedup vs baseline: 1.0305x; 1.0305x over previous
//
#include <hip/hip_runtime.h>
#include <math.h>

#define N_ROWS 8192
#define D_DIM  512
#define C_CLS  100

typedef unsigned short u16;
typedef unsigned int u32;
typedef __attribute__((ext_vector_type(8))) short short8;
typedef __attribute__((ext_vector_type(4))) float floatx4;

// ---------------- ws layout (float offsets), ~68.7 MB ----------------
#define WS_G      0                    // 512*512 fp32
#define WS_GP     262144               // 32 * 512*512 fp32 partials
#define WS_INV    8650752              // 8192
#define WS_WV     8658944              // 8192
#define WS_CLS    8667136              // 8192 (int)
#define WS_CNT    8675328              // 128 (int)
#define WS_OFFS   8675456              // 128 (int)
#define WS_CUR    8675584              // 128 (int)
#define WS_ORDER  8675712              // 8192 (int)
#define WS_NTH    8683904              // 512*8192 u16 = 2097152 floats
#define WS_NTL    10781056
#define WS_XTH    12878208
#define WS_XTL    14975360
#define WS_U      17072512             // 100*512
#define WS_V      17123712             // 100*512

// split fp32 -> bf16 hi (chop) + bf16 lo (chop of remainder); rel err ~2^-16
__device__ __forceinline__ void split2(float v, u16& h, u16& l) {
    unsigned u = __float_as_uint(v);
    h = (u16)(u >> 16);
    float r = v - __uint_as_float(u & 0xFFFF0000u);
    l = (u16)(__float_as_uint(r) >> 16);
}

// async global -> LDS, 16 B per lane (global_load_lds_dwordx4)
typedef const __attribute__((address_space(1))) u32* gp32;
typedef __attribute__((address_space(3))) u32* lp32;
__device__ __forceinline__ void cp16(const u16* g, u16* l) {
    __builtin_amdgcn_global_load_lds((gp32)g, (lp32)l, 16, 0, 0);
}

// -------- K1: per-row softmax max + argmax + int class counts --------
__global__ void k_softmax(const float* __restrict__ logits,
                          float* __restrict__ wv, int* __restrict__ cls,
                          int* __restrict__ cnt) {
    int wave = (blockIdx.x * blockDim.x + threadIdx.x) >> 6;
    int lane = threadIdx.x & 63;
    if (wave >= N_ROWS) return;
    const float* row = logits + (size_t)wave * C_CLS;
    float v1 = row[lane];
    bool has2 = (lane + 64) < C_CLS;
    float v2 = has2 ? row[lane + 64] : -INFINITY;
    float m; int idx;
    if (v2 > v1) { m = v2; idx = lane + 64; } else { m = v1; idx = lane; }
    #pragma unroll
    for (int off = 32; off >= 1; off >>= 1) {
        float om = __shfl_down(m, off);
        int   oi = __shfl_down(idx, off);
        if (om > m || (om == m && oi < idx)) { m = om; idx = oi; }
    }
    m = __shfl(m, 0);
    idx = __shfl(idx, 0);
    float s = expf(v1 - m) + (has2 ? expf(v2 - m) : 0.0f);
    #pragma unroll
    for (int off = 32; off >= 1; off >>= 1) s += __shfl_down(s, off);
    if (lane == 0) {
        wv[wave] = 1.0f / s;
        cls[wave] = idx;
        atomicAdd(&cnt[idx], 1);
    }
}

// -------- K2: per-row inverse norm --------
__global__ void k_norm(const float* __restrict__ x, float* __restrict__ inv) {
    int wave = (blockIdx.x * blockDim.x + threadIdx.x) >> 6;
    int lane = threadIdx.x & 63;
    if (wave >= N_ROWS) return;
    const float* row = x + (size_t)wave * D_DIM;
    float ss = 0.f;
    #pragma unroll
    for (int j = 0; j < D_DIM; j += 64) {
        float v = row[j + lane];
        ss += v * v;
    }
    #pragma unroll
    for (int off = 32; off >= 1; off >>= 1) ss += __shfl_down(ss, off);
    if (lane == 0) inv[wave] = 1.0f / fmaxf(sqrtf(ss), 1e-8f);
}

// -------- K3: parallel exclusive scan over class counts --------
__global__ void k_scan(const int* __restrict__ cnt, int* __restrict__ offs) {
    __shared__ int s[128];
    int t = threadIdx.x;
    int v = (t < C_CLS) ? cnt[t] : 0;
    s[t] = v;
    __syncthreads();
    #pragma unroll
    for (int d = 1; d < 128; d <<= 1) {
        int add = (t >= d) ? s[t - d] : 0;
        __syncthreads();
        s[t] += add;
        __syncthreads();
    }
    if (t < C_CLS) offs[t] = s[t] - v;
}

// -------- K4: scatter row indices into class-sorted order --------
__global__ void k_scatter(const int* __restrict__ cls, const int* __restrict__ offs,
                          int* __restrict__ cursor, int* __restrict__ order) {
    int m = blockIdx.x * 256 + threadIdx.x;
    int c = cls[m];
    int pos = atomicAdd(&cursor[c], 1);
    order[offs[c] + pos] = m;
}

// -------- K5: split + transpose: x -> xt hi/lo, (inv*x) -> nt hi/lo --------
#define LDT 65
__global__ __launch_bounds__(256) void k_convert(const float* __restrict__ x,
        const float* __restrict__ inv,
        u16* __restrict__ xth, u16* __restrict__ xtl,
        u16* __restrict__ nth, u16* __restrict__ ntl) {
    __shared__ unsigned xt_p[64 * LDT];
    __shared__ unsigned nt_p[64 * LDT];
    int r0 = blockIdx.x * 64, c0 = blockIdx.y * 64;
    int t = threadIdx.x;
    int r = t >> 2, cq = t & 3;
    const float* src = x + (size_t)(r0 + r) * D_DIM + c0 + cq * 16;
    float vv[16];
    {
        float4 a = *(const float4*)(src + 0);
        float4 b = *(const float4*)(src + 4);
        float4 c = *(const float4*)(src + 8);
        float4 d = *(const float4*)(src + 12);
        vv[0]=a.x; vv[1]=a.y; vv[2]=a.z; vv[3]=a.w;
        vv[4]=b.x; vv[5]=b.y; vv[6]=b.z; vv[7]=b.w;
        vv[8]=c.x; vv[9]=c.y; vv[10]=c.z; vv[11]=c.w;
        vv[12]=d.x; vv[13]=d.y; vv[14]=d.z; vv[15]=d.w;
    }
    float iv = inv[r0 + r];
    #pragma unroll
    for (int j = 0; j < 16; ++j) {
        u16 h, l, nh, nl;
        split2(vv[j], h, l);
        split2(iv * vv[j], nh, nl);
        int cl = cq * 16 + j;
        xt_p[cl * LDT + r] = ((unsigned)h  << 16) | l;
        nt_p[cl * LDT + r] = ((unsigned)nh << 16) | nl;
    }
    __syncthreads();
    int c = t >> 2, rq = (t & 3) * 16;
    size_t tbase = (size_t)(c0 + c) * N_ROWS + r0 + rq;
    {
        uint oh[8], ol[8];
        #pragma unroll
        for (int p = 0; p < 8; ++p) {
            unsigned d0 = xt_p[c * LDT + rq + 2*p];
            unsigned d1 = xt_p[c * LDT + rq + 2*p + 1];
            oh[p] = (d0 >> 16) | (d1 & 0xFFFF0000u);
            ol[p] = (d0 & 0xFFFFu) | (d1 << 16);
        }
        *(uint4*)&xth[tbase]     = make_uint4(oh[0], oh[1], oh[2], oh[3]);
        *(uint4*)&xth[tbase + 8] = make_uint4(oh[4], oh[5], oh[6], oh[7]);
        *(uint4*)&xtl[tbase]     = make_uint4(ol[0], ol[1], ol[2], ol[3]);
        *(uint4*)&xtl[tbase + 8] = make_uint4(ol[4], ol[5], ol[6], ol[7]);
    }
    {
        uint oh[8], ol[8];
        #pragma unroll
        for (int p = 0; p < 8; ++p) {
            unsigned d0 = nt_p[c * LDT + rq + 2*p];
            unsigned d1 = nt_p[c * LDT + rq + 2*p + 1];
            oh[p] = (d0 >> 16) | (d1 & 0xFFFF0000u);
            ol[p] = (d0 & 0xFFFFu) | (d1 << 16);
        }
        *(uint4*)&nth[tbase]     = make_uint4(oh[0], oh[1], oh[2], oh[3]);
        *(uint4*)&nth[tbase + 8] = make_uint4(oh[4], oh[5], oh[6], oh[7]);
        *(uint4*)&ntl[tbase]     = make_uint4(ol[0], ol[1], ol[2], ol[3]);
        *(uint4*)&ntl[tbase + 8] = make_uint4(ol[4], ol[5], ol[6], ol[7]);
    }
}

// -------- K6: G_part = nt^T @ xt, 128x128 tiles, splitK=32 --------
__global__ __launch_bounds__(256, 2) void k_gemm1(const u16* __restrict__ nth,
        const u16* __restrict__ ntl, const u16* __restrict__ xth,
        const u16* __restrict__ xtl, float* __restrict__ Gp) {
    __shared__ __attribute__((aligned(16))) u16 Ah[128*32], Al[128*32];
    __shared__ __attribute__((aligned(16))) u16 Bh[128*32], Bl[128*32];
    int i0 = (blockIdx.x & 3) << 7, j0 = (blockIdx.x >> 2) << 7;
    int kb = blockIdx.y << 8;
    int t = threadIdx.x, w = t >> 6, l = t & 63;
    int srow = t >> 2, scol = (t & 3) << 3;
    int lm = l & 15, lg = l >> 4;
    floatx4 acc[4][4];
    #pragma unroll
    for (int mi = 0; mi < 4; ++mi)
        #pragma unroll
        for (int ni = 0; ni < 4; ++ni) acc[mi][ni] = (floatx4){0.f,0.f,0.f,0.f};
    int d0 = srow * 32 + scol;
    int d1 = (64 + srow) * 32 + scol;
    const size_t ga0 = (size_t)(i0 + srow) * N_ROWS + kb + scol;
    const size_t ga1 = (size_t)(i0 + 64 + srow) * N_ROWS + kb + scol;
    const size_t gb0 = (size_t)(j0 + srow) * N_ROWS + kb + scol;
    const size_t gb1 = (size_t)(j0 + 64 + srow) * N_ROWS + kb + scol;
    for (int s = 0; s < 8; ++s) {
        int ks = s << 5;
        cp16(nth + ga0 + ks, Ah + d0);
        cp16(nth + ga1 + ks, Ah + d1);
        cp16(ntl + ga0 + ks, Al + d0);
        cp16(ntl + ga1 + ks, Al + d1);
        cp16(xth + gb0 + ks, Bh + d0);
        cp16(xth + gb1 + ks, Bh + d1);
        cp16(xtl + gb0 + ks, Bl + d0);
        cp16(xtl + gb1 + ks, Bl + d1);
        __syncthreads();
        short8 ah[4], al[4], bh[4], bl[4];
        #pragma unroll
        for (int mi = 0; mi < 4; ++mi) {
            int off = (((w & 1) << 6) + (mi << 4) + lm) * 32 + (lg << 3);
            ah[mi] = *(const short8*)&Ah[off];
            al[mi] = *(const short8*)&Al[off];
        }
        #pragma unroll
        for (int ni = 0; ni < 4; ++ni) {
            int off = (((w >> 1) << 6) + (ni << 4) + lm) * 32 + (lg << 3);
            bh[ni] = *(const short8*)&Bh[off];
            bl[ni] = *(const short8*)&Bl[off];
        }
        #pragma unroll
        for (int mi = 0; mi < 4; ++mi)
            #pragma unroll
            for (int ni = 0; ni < 4; ++ni) {
                acc[mi][ni] = __builtin_amdgcn_mfma_f32_16x16x32_bf16(ah[mi], bh[ni], acc[mi][ni], 0, 0, 0);
                acc[mi][ni] = __builtin_amdgcn_mfma_f32_16x16x32_bf16(ah[mi], bl[ni], acc[mi][ni], 0, 0, 0);
                acc[mi][ni] = __builtin_amdgcn_mfma_f32_16x16x32_bf16(al[mi], bh[ni], acc[mi][ni], 0, 0, 0);
            }
        __syncthreads();
    }
    float* Gb = Gp + ((size_t)blockIdx.y << 18);
    #pragma unroll
    for (int mi = 0; mi < 4; ++mi) {
        int row0 = i0 + ((w & 1) << 6) + (mi << 4) + (lg << 2);
        #pragma unroll
        for (int ni = 0; ni < 4; ++ni) {
            int col = j0 + ((w >> 1) << 6) + (ni << 4) + lm;
            #pragma unroll
            for (int r = 0; r < 4; ++r)
                Gb[(size_t)(row0 + r) * D_DIM + col] = acc[mi][ni][r];
        }
    }
}

// -------- K7: G = sum of 32 partials --------
__global__ void k_reduceG(const float* __restrict__ Gp, float* __restrict__ G) {
    int i = blockIdx.x * 256 + threadIdx.x;
    float s = 0.f;
    #pragma unroll
    for (int p = 0; p < 32; ++p) s += Gp[(size_t)p * (D_DIM * D_DIM) + i];
    G[i] = s;
}

// -------- K8: per-class u,v reductions (column-chunked) --------
// grid (100, 8): block = class c, 64 cols; 256 thr = 4 row-groups x 64 lanes
__global__ __launch_bounds__(256) void k_uv(const float* __restrict__ x,
        const float* __restrict__ inv, const float* __restrict__ wv,
        const int* __restrict__ order, const int* __restrict__ offs,
        const int* __restrict__ cnt, float* __restrict__ u, float* __restrict__ v) {
    __shared__ float us[4][64], vs[4][64];
    int c = blockIdx.x, jc = blockIdx.y;
    int t = threadIdx.x, g = t >> 6, lane = t & 63;
    int j = jc * 64 + lane;
    int n = cnt[c], o = offs[c];
    float ua = 0.f, va = 0.f;
    for (int p = g; p < n; p += 4) {
        int m = order[o + p];
        float wm = wv[m];
        float wi = wm * inv[m];
        float xv = x[(size_t)m * D_DIM + j];
        ua += wi * xv; va += wm * xv;
    }
    us[g][lane] = ua; vs[g][lane] = va;
    __syncthreads();
    if (g == 0) {
        float uu = us[0][lane] + us[1][lane] + us[2][lane] + us[3][lane];
        float vv2 = vs[0][lane] + vs[1][lane] + vs[2][lane] + vs[3][lane];
        u[(size_t)c * D_DIM + j] = uu;
        v[(size_t)c * D_DIM + j] = vv2;
    }
}

// -------- K9: protos[c][j] = (v[c][j] + sum_k u[c][k]*G[k][j]) / n --------
// one thread per output; u-row in LDS; G reads coalesced across j.
__global__ __launch_bounds__(256) void k_pgemm(const float* __restrict__ u,
        const float* __restrict__ v, const int* __restrict__ cnt,
        const float* __restrict__ G, float* __restrict__ out) {
    __shared__ float us[D_DIM];
    int c = blockIdx.x >> 1;
    int j = ((blockIdx.x & 1) << 8) + threadIdx.x;
    us[threadIdx.x]       = u[(size_t)c * D_DIM + threadIdx.x];
    us[threadIdx.x + 256] = u[(size_t)c * D_DIM + threadIdx.x + 256];
    __syncthreads();
    float acc = v[(size_t)c * D_DIM + j];
    #pragma unroll 8
    for (int k = 0; k < D_DIM; ++k)
        acc += us[k] * G[(size_t)k * D_DIM + j];
    int n = cnt[c];
    float s = (n > 0) ? 1.0f / (float)n : 0.0f;
    out[(size_t)c * D_DIM + j] = acc * s;
}

// -------- K10: inter[i,j,d] = proto[j,d] - proto[i,d] --------
__global__ void k_inter(const float* __restrict__ proto, float* __restrict__ out) {
    int pair = blockIdx.x;
    int i = pair / C_CLS;
    int j = pair - i * C_CLS;
    int d = threadIdx.x << 2;
    float4 pj = *(const float4*)&proto[j * D_DIM + d];
    float4 pi = *(const float4*)&proto[i * D_DIM + d];
    float4 r;
    r.x = pj.x - pi.x; r.y = pj.y - pi.y; r.z = pj.z - pi.z; r.w = pj.w - pi.w;
    *(float4*)&out[(size_t)pair * D_DIM + d] = r;
}

extern "C" void kernel_launch(void* const* d_in, const int* in_sizes, int n_in,
                              void* d_out, int out_size, void* d_ws, size_t ws_size,
                              hipStream_t stream) {
    const float* x      = (const float*)d_in[0];   // [8192, 512]
    const float* logits = (const float*)d_in[1];   // [8192, 100]
    float* out = (float*)d_out;
    float* ws  = (float*)d_ws;
    float* G     = ws + WS_G;
    float* Gp    = ws + WS_GP;
    float* inv   = ws + WS_INV;
    float* wv    = ws + WS_WV;
    int*   cls   = (int*)(ws + WS_CLS);
    int*   cnt   = (int*)(ws + WS_CNT);
    int*   offs  = (int*)(ws + WS_OFFS);
    int*   cur   = (int*)(ws + WS_CUR);
    int*   order = (int*)(ws + WS_ORDER);
    u16* nth = (u16*)(ws + WS_NTH);
    u16* ntl = (u16*)(ws + WS_NTL);
    u16* xth = (u16*)(ws + WS_XTH);
    u16* xtl = (u16*)(ws + WS_XTL);
    float* u_arr = ws + WS_U;
    float* v_arr = ws + WS_V;

    hipMemsetAsync((void*)cnt, 0, 384 * sizeof(int), stream);
    k_softmax<<<N_ROWS / 4, 256, 0, stream>>>(logits, wv, cls, cnt);
    k_norm<<<N_ROWS / 4, 256, 0, stream>>>(x, inv);
    k_scan<<<1, 128, 0, stream>>>(cnt, offs);
    k_scatter<<<N_ROWS / 256, 256, 0, stream>>>(cls, offs, cur, order);
    k_convert<<<dim3(128, 8), 256, 0, stream>>>(x, inv, xth, xtl, nth, ntl);
    k_gemm1<<<dim3(16, 32), 256, 0, stream>>>(nth, ntl, xth, xtl, Gp);
    k_reduceG<<<D_DIM * D_DIM / 256, 256, 0, stream>>>(Gp, G);
    k_uv<<<dim3(C_CLS, 8), 256, 0, stream>>>(x, inv, wv, order, offs, cnt, u_arr, v_arr);
    k_pgemm<<<C_CLS * 2, 256, 0, stream>>>(u_arr, v_arr, cnt, G, out);
    k_inter<<<C_CLS * C_CLS, 128, 0, stream>>>(out, out + C_CLS * D_DIM);
}

// Round 5
// 178.772 us; speedup vs baseline: 1.1524x; 1.1183x over previous
//
#include <hip/hip_runtime.h>
#include <math.h>

#define N_ROWS 8192
#define D_DIM  512
#define C_CLS  100

typedef unsigned short u16;
typedef unsigned int u32;
typedef __attribute__((ext_vector_type(8))) short short8;
typedef __attribute__((ext_vector_type(4))) float floatx4;

// ---------------- ws layout (float offsets), ~39.4 MB ----------------
#define WS_G      0              // 512*512 fp32 (full, mirrored)
#define WS_GP     262144         // 32 * 10 * 128*128 fp32 upper-tile partials
#define WS_INV    5505024        // 8192
#define WS_SINV   5513216        // 8192 sqrt(inv)
#define WS_WV     5521408        // 8192
#define WS_CLS    5529600        // 8192 (int)
#define WS_CNT    5537792        // 128 (int)
#define WS_OFFS   5537920        // 128 (int)
#define WS_ORDER  5538048        // 8192 (int)
#define WS_ZTH    5546240        // 512*8192 u16 (2097152 floats)
#define WS_ZTL    7643392
#define WS_U      9740544        // 100*512
#define WS_V      9791744        // 100*512

// split fp32 -> bf16 hi (chop) + bf16 lo (chop of remainder); rel err ~2^-16
__device__ __forceinline__ void split2(float v, u16& h, u16& l) {
    unsigned u = __float_as_uint(v);
    h = (u16)(u >> 16);
    float r = v - __uint_as_float(u & 0xFFFF0000u);
    l = (u16)(__float_as_uint(r) >> 16);
}

// async global -> LDS, 16 B per lane (global_load_lds_dwordx4)
typedef const __attribute__((address_space(1))) u32* gp32;
typedef __attribute__((address_space(3))) u32* lp32;
__device__ __forceinline__ void cp16(const u16* g, u16* l) {
    __builtin_amdgcn_global_load_lds((gp32)g, (lp32)l, 16, 0, 0);
}

// -------- K1: fused softmax stats + row norms (one wave per row, both) ----
__global__ __launch_bounds__(256) void k_prep(const float* __restrict__ logits,
        const float* __restrict__ x, float* __restrict__ wv,
        int* __restrict__ cls, float* __restrict__ inv, float* __restrict__ sinv) {
    int wave = (blockIdx.x * blockDim.x + threadIdx.x) >> 6;
    int lane = threadIdx.x & 63;
    if (wave >= N_ROWS) return;
    // --- softmax max / argmax / denom over logits row ---
    const float* row = logits + (size_t)wave * C_CLS;
    float v1 = row[lane];
    bool has2 = (lane + 64) < C_CLS;
    float v2 = has2 ? row[lane + 64] : -INFINITY;
    float m; int idx;
    if (v2 > v1) { m = v2; idx = lane + 64; } else { m = v1; idx = lane; }
    #pragma unroll
    for (int off = 32; off >= 1; off >>= 1) {
        float om = __shfl_down(m, off);
        int   oi = __shfl_down(idx, off);
        if (om > m || (om == m && oi < idx)) { m = om; idx = oi; }
    }
    m = __shfl(m, 0);
    idx = __shfl(idx, 0);
    float s = expf(v1 - m) + (has2 ? expf(v2 - m) : 0.0f);
    #pragma unroll
    for (int off = 32; off >= 1; off >>= 1) s += __shfl_down(s, off);
    // --- row norm of x ---
    const float* xr = x + (size_t)wave * D_DIM;
    float ss = 0.f;
    #pragma unroll
    for (int j = 0; j < D_DIM; j += 64) {
        float v = xr[j + lane];
        ss += v * v;
    }
    #pragma unroll
    for (int off = 32; off >= 1; off >>= 1) ss += __shfl_down(ss, off);
    if (lane == 0) {
        wv[wave] = 1.0f / s;
        cls[wave] = idx;
        float iv = 1.0f / fmaxf(sqrtf(ss), 1e-8f);
        inv[wave] = iv;
        sinv[wave] = sqrtf(iv);
    }
}

// -------- K2: blocks 0..1023: split+transpose z = sinv*x; block 1024: sort --
#define LDT 65
__global__ __launch_bounds__(256) void k_mid(const float* __restrict__ x,
        const float* __restrict__ sinv, const int* __restrict__ cls,
        u16* __restrict__ zth, u16* __restrict__ ztl,
        int* __restrict__ cnt, int* __restrict__ offs, int* __restrict__ order) {
    __shared__ unsigned zt_p[64 * LDT];
    int bx = blockIdx.x;
    int t = threadIdx.x;
    if (bx == 1024) {
        // histogram + exclusive scan + scatter (single block)
        __shared__ int hist[128], scan_s[128], cur[128];
        if (t < 128) hist[t] = 0;
        __syncthreads();
        for (int m2 = t; m2 < N_ROWS; m2 += 256) atomicAdd(&hist[cls[m2]], 1);
        __syncthreads();
        if (t < 128) scan_s[t] = hist[t];
        __syncthreads();
        #pragma unroll
        for (int d = 1; d < 128; d <<= 1) {
            int add = 0;
            if (t < 128 && t >= d) add = scan_s[t - d];
            __syncthreads();
            if (t < 128) scan_s[t] += add;
            __syncthreads();
        }
        if (t < 128) {
            int off0 = scan_s[t] - hist[t];
            cur[t] = off0;
            offs[t] = off0;
            cnt[t] = hist[t];
        }
        __syncthreads();
        for (int m2 = t; m2 < N_ROWS; m2 += 256) {
            int c2 = cls[m2];
            int p = atomicAdd(&cur[c2], 1);
            order[p] = m2;
        }
        return;
    }
    int r0 = (bx & 127) << 6, c0 = (bx >> 7) << 6;
    int r = t >> 2, cq = t & 3;
    const float* src = x + (size_t)(r0 + r) * D_DIM + c0 + cq * 16;
    float vv[16];
    {
        float4 a = *(const float4*)(src + 0);
        float4 b = *(const float4*)(src + 4);
        float4 c = *(const float4*)(src + 8);
        float4 d = *(const float4*)(src + 12);
        vv[0]=a.x; vv[1]=a.y; vv[2]=a.z; vv[3]=a.w;
        vv[4]=b.x; vv[5]=b.y; vv[6]=b.z; vv[7]=b.w;
        vv[8]=c.x; vv[9]=c.y; vv[10]=c.z; vv[11]=c.w;
        vv[12]=d.x; vv[13]=d.y; vv[14]=d.z; vv[15]=d.w;
    }
    float sv = sinv[r0 + r];
    #pragma unroll
    for (int j = 0; j < 16; ++j) {
        u16 h, l;
        split2(sv * vv[j], h, l);
        zt_p[(cq * 16 + j) * LDT + r] = ((unsigned)h << 16) | l;
    }
    __syncthreads();
    int c = t >> 2, rq = (t & 3) * 16;
    size_t tbase = (size_t)(c0 + c) * N_ROWS + r0 + rq;
    uint oh[8], ol[8];
    #pragma unroll
    for (int p = 0; p < 8; ++p) {
        unsigned d0 = zt_p[c * LDT + rq + 2*p];
        unsigned d1 = zt_p[c * LDT + rq + 2*p + 1];
        oh[p] = (d0 >> 16) | (d1 & 0xFFFF0000u);
        ol[p] = (d0 & 0xFFFFu) | (d1 << 16);
    }
    *(uint4*)&zth[tbase]     = make_uint4(oh[0], oh[1], oh[2], oh[3]);
    *(uint4*)&zth[tbase + 8] = make_uint4(oh[4], oh[5], oh[6], oh[7]);
    *(uint4*)&ztl[tbase]     = make_uint4(ol[0], ol[1], ol[2], ol[3]);
    *(uint4*)&ztl[tbase + 8] = make_uint4(ol[4], ol[5], ol[6], ol[7]);
}

// -------- K3: blocks 0..319: Gp = z^T z upper tiles (splitK=32);
//             blocks 320..1119: per-class u,v reductions --------
__global__ __launch_bounds__(256) void k_big(const u16* __restrict__ zth,
        const u16* __restrict__ ztl, const float* __restrict__ x,
        const float* __restrict__ inv, const float* __restrict__ wv,
        const int* __restrict__ order, const int* __restrict__ offs,
        const int* __restrict__ cnt, float* __restrict__ Gp,
        float* __restrict__ u, float* __restrict__ v) {
    __shared__ __attribute__((aligned(16))) u16 Ah[128*32], Al[128*32];
    __shared__ __attribute__((aligned(16))) u16 Bh[128*32], Bl[128*32];
    __shared__ float us[4][64], vs[4][64];
    int bx = blockIdx.x;
    int t = threadIdx.x;
    if (bx >= 320) {
        // ---- u/v class reduction ----
        int idx = bx - 320;
        int c = idx >> 3, jc = idx & 7;
        int g = t >> 6, lane = t & 63;
        int j = jc * 64 + lane;
        int n = cnt[c], o = offs[c];
        float ua = 0.f, va = 0.f;
        for (int p = g; p < n; p += 4) {
            int m = order[o + p];
            float wm = wv[m];
            float wi = wm * inv[m];
            float xv = x[(size_t)m * D_DIM + j];
            ua += wi * xv; va += wm * xv;
        }
        us[g][lane] = ua; vs[g][lane] = va;
        __syncthreads();
        if (g == 0) {
            u[(size_t)c * D_DIM + j] = us[0][lane] + us[1][lane] + us[2][lane] + us[3][lane];
            v[(size_t)c * D_DIM + j] = vs[0][lane] + vs[1][lane] + vs[2][lane] + vs[3][lane];
        }
        return;
    }
    // ---- gemm: tile in upper triangle, splitK ----
    int tile = bx % 10;
    int p = bx / 10;                    // 0..31
    int ti = tile < 4 ? 0 : (tile < 7 ? 1 : (tile < 9 ? 2 : 3));
    int tj = tile - (ti == 0 ? 0 : (ti == 1 ? 3 : (ti == 2 ? 5 : 6)));
    int i0 = ti << 7, j0 = tj << 7;
    bool diag = (ti == tj);
    int kb = p << 8;
    int w = t >> 6, l = t & 63;
    int srow = t >> 2, scol = (t & 3) << 3;
    int lm = l & 15, lg = l >> 4;
    floatx4 acc[4][4];
    #pragma unroll
    for (int mi = 0; mi < 4; ++mi)
        #pragma unroll
        for (int ni = 0; ni < 4; ++ni) acc[mi][ni] = (floatx4){0.f,0.f,0.f,0.f};
    int d0 = srow * 32 + scol;
    int d1 = (64 + srow) * 32 + scol;
    const size_t ga0 = (size_t)(i0 + srow) * N_ROWS + kb + scol;
    const size_t ga1 = (size_t)(i0 + 64 + srow) * N_ROWS + kb + scol;
    const size_t gb0 = (size_t)(j0 + srow) * N_ROWS + kb + scol;
    const size_t gb1 = (size_t)(j0 + 64 + srow) * N_ROWS + kb + scol;
    const u16* Bhs = diag ? Ah : Bh;
    const u16* Bls = diag ? Al : Bl;
    for (int s = 0; s < 8; ++s) {
        int ks = s << 5;
        cp16(zth + ga0 + ks, Ah + d0);
        cp16(zth + ga1 + ks, Ah + d1);
        cp16(ztl + ga0 + ks, Al + d0);
        cp16(ztl + ga1 + ks, Al + d1);
        if (!diag) {
            cp16(zth + gb0 + ks, Bh + d0);
            cp16(zth + gb1 + ks, Bh + d1);
            cp16(ztl + gb0 + ks, Bl + d0);
            cp16(ztl + gb1 + ks, Bl + d1);
        }
        __syncthreads();
        short8 ah[4], al[4], bh[4], bl[4];
        #pragma unroll
        for (int mi = 0; mi < 4; ++mi) {
            int off = (((w & 1) << 6) + (mi << 4) + lm) * 32 + (lg << 3);
            ah[mi] = *(const short8*)&Ah[off];
            al[mi] = *(const short8*)&Al[off];
        }
        #pragma unroll
        for (int ni = 0; ni < 4; ++ni) {
            int off = (((w >> 1) << 6) + (ni << 4) + lm) * 32 + (lg << 3);
            bh[ni] = *(const short8*)&Bhs[off];
            bl[ni] = *(const short8*)&Bls[off];
        }
        #pragma unroll
        for (int mi = 0; mi < 4; ++mi)
            #pragma unroll
            for (int ni = 0; ni < 4; ++ni) {
                acc[mi][ni] = __builtin_amdgcn_mfma_f32_16x16x32_bf16(ah[mi], bh[ni], acc[mi][ni], 0, 0, 0);
                acc[mi][ni] = __builtin_amdgcn_mfma_f32_16x16x32_bf16(ah[mi], bl[ni], acc[mi][ni], 0, 0, 0);
                acc[mi][ni] = __builtin_amdgcn_mfma_f32_16x16x32_bf16(al[mi], bh[ni], acc[mi][ni], 0, 0, 0);
            }
        __syncthreads();
    }
    float* Gb = Gp + ((size_t)(p * 10 + tile) << 14);
    #pragma unroll
    for (int mi = 0; mi < 4; ++mi) {
        int row0 = ((w & 1) << 6) + (mi << 4) + (lg << 2);
        #pragma unroll
        for (int ni = 0; ni < 4; ++ni) {
            int col = ((w >> 1) << 6) + (ni << 4) + lm;
            #pragma unroll
            for (int r = 0; r < 4; ++r)
                Gb[(size_t)(row0 + r) * 128 + col] = acc[mi][ni][r];
        }
    }
}

// -------- K4: G[r][c] = sum_p Gp[p][uppertile(r,c)] (mirror lower) --------
__global__ void k_reduceG(const float* __restrict__ Gp, float* __restrict__ G) {
    int i = blockIdx.x * 256 + threadIdx.x;
    int r = i >> 9, c = i & 511;
    int tr = r >> 7, tc = c >> 7, rr = r & 127, cc = c & 127;
    if (tr > tc) { int tmp = tr; tr = tc; tc = tmp; tmp = rr; rr = cc; cc = tmp; }
    int tid = tr * 4 + tc - ((tr * (tr + 1)) >> 1);
    const float* src = Gp + ((size_t)tid << 14) + rr * 128 + cc;
    float s = 0.f;
    #pragma unroll
    for (int p = 0; p < 32; ++p) s += src[(size_t)p * 163840];
    G[i] = s;
}

// -------- K5: protos[c][j] = (v[c][j] + sum_k u[c][k]*G[k][j]) / n --------
__global__ __launch_bounds__(256) void k_pgemm(const float* __restrict__ u,
        const float* __restrict__ v, const int* __restrict__ cnt,
        const float* __restrict__ G, float* __restrict__ out) {
    __shared__ float us[D_DIM];
    int c = blockIdx.x >> 1;
    int j = ((blockIdx.x & 1) << 8) + threadIdx.x;
    us[threadIdx.x]       = u[(size_t)c * D_DIM + threadIdx.x];
    us[threadIdx.x + 256] = u[(size_t)c * D_DIM + threadIdx.x + 256];
    __syncthreads();
    float acc = v[(size_t)c * D_DIM + j];
    #pragma unroll 8
    for (int k = 0; k < D_DIM; ++k)
        acc += us[k] * G[(size_t)k * D_DIM + j];
    int n = cnt[c];
    float s = (n > 0) ? 1.0f / (float)n : 0.0f;
    out[(size_t)c * D_DIM + j] = acc * s;
}

// -------- K6: inter[i,j,d] = proto[j,d] - proto[i,d] --------
__global__ void k_inter(const float* __restrict__ proto, float* __restrict__ out) {
    int pair = blockIdx.x;
    int i = pair / C_CLS;
    int j = pair - i * C_CLS;
    int d = threadIdx.x << 2;
    float4 pj = *(const float4*)&proto[j * D_DIM + d];
    float4 pi = *(const float4*)&proto[i * D_DIM + d];
    float4 r;
    r.x = pj.x - pi.x; r.y = pj.y - pi.y; r.z = pj.z - pi.z; r.w = pj.w - pi.w;
    *(float4*)&out[(size_t)pair * D_DIM + d] = r;
}

extern "C" void kernel_launch(void* const* d_in, const int* in_sizes, int n_in,
                              void* d_out, int out_size, void* d_ws, size_t ws_size,
                              hipStream_t stream) {
    const float* x      = (const float*)d_in[0];   // [8192, 512]
    const float* logits = (const float*)d_in[1];   // [8192, 100]
    float* out = (float*)d_out;
    float* ws  = (float*)d_ws;
    float* G     = ws + WS_G;
    float* Gp    = ws + WS_GP;
    float* inv   = ws + WS_INV;
    float* sinv  = ws + WS_SINV;
    float* wv    = ws + WS_WV;
    int*   cls   = (int*)(ws + WS_CLS);
    int*   cnt   = (int*)(ws + WS_CNT);
    int*   offs  = (int*)(ws + WS_OFFS);
    int*   order = (int*)(ws + WS_ORDER);
    u16* zth = (u16*)(ws + WS_ZTH);
    u16* ztl = (u16*)(ws + WS_ZTL);
    float* u_arr = ws + WS_U;
    float* v_arr = ws + WS_V;

    k_prep<<<N_ROWS / 4, 256, 0, stream>>>(logits, x, wv, cls, inv, sinv);
    k_mid<<<1025, 256, 0, stream>>>(x, sinv, cls, zth, ztl, cnt, offs, order);
    k_big<<<1120, 256, 0, stream>>>(zth, ztl, x, inv, wv, order, offs, cnt, Gp, u_arr, v_arr);
    k_reduceG<<<D_DIM * D_DIM / 256, 256, 0, stream>>>(Gp, G);
    k_pgemm<<<C_CLS * 2, 256, 0, stream>>>(u_arr, v_arr, cnt, G, out);
    k_inter<<<C_CLS * C_CLS, 128, 0, stream>>>(out, out + C_CLS * D_DIM);
}